// Round 3
// baseline (308.081 us; speedup 1.0000x reference)
//
#include <hip/hip_runtime.h>
#include <math.h>
#include <stdint.h>

typedef __attribute__((ext_vector_type(8))) short bf16x8;
typedef __attribute__((ext_vector_type(4))) float f32x4;

__device__ __forceinline__ unsigned short f2bf(float f) {
    union { float f; uint32_t u; } c; c.f = f;
    uint32_t u = c.u;
    u += 0x7FFFu + ((u >> 16) & 1u);
    return (unsigned short)(u >> 16);
}
__device__ __forceinline__ uint32_t pack2(float a, float b) {
    return (uint32_t)f2bf(a) | ((uint32_t)f2bf(b) << 16);
}
__device__ __forceinline__ float silu_f(float x) {
    return x / (1.0f + __expf(-x));
}

// Uniform cardinal cubic B-spline bases on grid g_i = -2.2 + 0.4*i.
// b[v] = N3((x+2.2)/0.4 - v), N3(s) = (max(2-|s-2|,0)^3 - 4*max(1-|s-2|,0)^3)/6.
// Identical to the reference Cox-de-Boor recursion on this uniform grid.
__device__ __forceinline__ void bspline8(float x, float* __restrict__ b) {
    const float tt = (x + 2.2f) * 2.5f;
#pragma unroll
    for (int v = 0; v < 8; ++v) {
        float y = fabsf(tt - (float)(v + 2));
        float p = fmaxf(2.0f - y, 0.0f);
        float q = fmaxf(1.0f - y, 0.0f);
        b[v] = (p * p * p - 4.0f * q * q * q) * (1.0f / 6.0f);
    }
}

// ---------------------------------------------------------------------------
// prep kernels
// ---------------------------------------------------------------------------
__global__ __launch_bounds__(256) void prep_ftw(const float* __restrict__ ftw,
                                                unsigned short* __restrict__ Wb) {
    const int idx = blockIdx.x * 256 + threadIdx.x;   // 98304 = 128*768
    Wb[idx] = f2bf(ftw[idx]);
}

__global__ __launch_bounds__(256) void prep_bp(const float* __restrict__ bw,
                                               const float* __restrict__ sw,
                                               unsigned short* __restrict__ Bp) {
    const int idx = blockIdx.x * 256 + threadIdx.x;   // 524288 = 128*4096
    const int n = idx >> 12;
    const int k = idx & 4095;
    const int f = k >> 4;
    const int v = k & 15;
    float val = 0.f;
    if (v == 0) val = bw[n * 256 + f];
    else if (v <= 8) val = sw[(size_t)(n * 256 + f) * 8 + (v - 1)];
    Bp[idx] = f2bf(val);
}

// ---------------------------------------------------------------------------
// FT GEMM (bf16 MFMA), BM=64, BK=64, reg-prefetch double buffer.
// Output TRANSPOSED: HT[c][r], c = side*128 + o   (coalesces kan1's reads)
// grid (512, 2), block 256 (4 waves as 2x2; wave tile 32 rows x 64 cols)
// ---------------------------------------------------------------------------
__global__ __launch_bounds__(256) void ft_mfma(
        const float* __restrict__ stm, const float* __restrict__ nstm,
        const unsigned short* __restrict__ Wb, const float* __restrict__ bias,
        float* __restrict__ HT) {
    __shared__ char lds[24576];          // smA 8 KB | smB 16 KB
    char* smA = lds;
    char* smB = lds + 8192;
    const int side = blockIdx.y;
    const float* __restrict__ A = side ? nstm : stm;
    const int r0 = blockIdx.x * 64;
    const int t = threadIdx.x;
    const int lane = t & 63, wid = t >> 6;
    const int wr = wid >> 1, wc = wid & 1;
    const int fr = lane & 15;
    const int h = lane >> 4;             // 0..3
    const int fkb = h * 8;

    const int arow = t >> 2, ako = (t & 3) * 4;   // A: 4x float4, elem ako+q*16
    const int bcol = t >> 1, bko = (t & 1) * 8;   // B: 4x int4 (8 bf16), elem bko+q*16

    const float* agp = &A[(size_t)(r0 + arow) * 768 + ako];
    const unsigned short* bgp = &Wb[(size_t)bcol * 768 + bko];

    float4 pa[4];
    int4 pb[4];
#define FT_LOAD(k0)                                                            \
    {                                                                          \
        _Pragma("unroll") for (int q = 0; q < 4; ++q)                          \
            pa[q] = *reinterpret_cast<const float4*>(&agp[(k0) + q * 16]);     \
        _Pragma("unroll") for (int q = 0; q < 4; ++q)                          \
            pb[q] = *reinterpret_cast<const int4*>(&bgp[(k0) + q * 16]);       \
    }

    f32x4 acc[2][4];
#pragma unroll
    for (int mt = 0; mt < 2; ++mt)
#pragma unroll
        for (int nt = 0; nt < 4; ++nt) acc[mt][nt] = (f32x4){0.f, 0.f, 0.f, 0.f};

    FT_LOAD(0);
    for (int k0 = 0; k0 < 768; k0 += 64) {
        // write staged regs to LDS (cvt A fp32->bf16)
#pragma unroll
        for (int q = 0; q < 4; ++q) {
            uint32_t off = ((uint32_t)arow * 128u + (uint32_t)(ako + q * 16) * 2u) ^
                           ((uint32_t)(arow & 7) << 4);
            int2 w;
            w.x = (int)pack2(pa[q].x, pa[q].y);
            w.y = (int)pack2(pa[q].z, pa[q].w);
            *reinterpret_cast<int2*>(smA + off) = w;
        }
#pragma unroll
        for (int q = 0; q < 4; ++q) {
            uint32_t off = ((uint32_t)bcol * 128u + (uint32_t)(bko + q * 16) * 2u) ^
                           ((uint32_t)(bcol & 7) << 4);
            *reinterpret_cast<int4*>(smB + off) = pb[q];
        }
        __syncthreads();
        if (k0 + 64 < 768) FT_LOAD(k0 + 64);   // prefetch next tile (flies under MFMA)
#pragma unroll
        for (int ks = 0; ks < 2; ++ks) {
            const int kb = ks * 32 + fkb;
            bf16x8 a[2], b[4];
#pragma unroll
            for (int mt = 0; mt < 2; ++mt) {
                uint32_t row = (uint32_t)(wr * 32 + mt * 16 + fr);
                uint32_t off = (row * 128u + (uint32_t)kb * 2u) ^ ((row & 7u) << 4);
                a[mt] = *reinterpret_cast<const bf16x8*>(smA + off);
            }
#pragma unroll
            for (int nt = 0; nt < 4; ++nt) {
                uint32_t col = (uint32_t)(wc * 64 + nt * 16 + fr);
                uint32_t off = (col * 128u + (uint32_t)kb * 2u) ^ ((col & 7u) << 4);
                b[nt] = *reinterpret_cast<const bf16x8*>(smB + off);
            }
#pragma unroll
            for (int mt = 0; mt < 2; ++mt)
#pragma unroll
                for (int nt = 0; nt < 4; ++nt)
                    acc[mt][nt] = __builtin_amdgcn_mfma_f32_16x16x32_bf16(
                        a[mt], b[nt], acc[mt][nt], 0, 0, 0);
        }
        __syncthreads();
    }
    // epilogue: HT[c][r], float4 over 4 consecutive rows (C/D: col=lane&15, row=h*4+j)
#pragma unroll
    for (int nt = 0; nt < 4; ++nt) {
        const int colL = wc * 64 + nt * 16 + fr;
        const float bv = bias[colL];
        const size_t cg = (size_t)(side * 128 + colL) * 32768;
#pragma unroll
        for (int mt = 0; mt < 2; ++mt) {
            const int row = r0 + wr * 32 + mt * 16 + h * 4;
            float4 o;
            o.x = acc[mt][nt][0] + bv; o.y = acc[mt][nt][1] + bv;
            o.z = acc[mt][nt][2] + bv; o.w = acc[mt][nt][3] + bv;
            *reinterpret_cast<float4*>(&HT[cg + row]) = o;
        }
    }
}

// ---------------------------------------------------------------------------
// KAN1 (bf16 MFMA, expanded A, K=256*16) + fused KAN2 + sigmoid.
// BM=64, K-step=128 (8 features), grid 512, block 256 (4 waves as 2x2).
// ---------------------------------------------------------------------------
__global__ __launch_bounds__(256) void kan1_fused(
        const float* __restrict__ HT,           // 256 x 32768 f32 (transposed)
        const unsigned short* __restrict__ Bp,  // 128 x 4096 bf16 (padded)
        const float* __restrict__ w2b,          // 128
        const float* __restrict__ w2s,          // 128 x 8
        float* __restrict__ out) {              // 32768
    __shared__ char lds[49152];   // smP 16 KB | smB 32 KB ; epilogue: smH 64x132 f32
    char* smP = lds;
    char* smB = lds + 16384;
    float* smH = (float*)lds;
    const int r0 = blockIdx.x * 64;
    const int t = threadIdx.x;
    const int lane = t & 63, wid = t >> 6;
    const int wr = wid >> 1, wc = wid & 1;
    const int fr = lane & 15;
    const int h = lane >> 4;
    const int fkb = h * 8;

    const int xrow = t & 63, xf0 = t >> 6;        // x loads: coalesced over rows
    const int bn = t >> 1, bk0 = (t & 1) * 64;    // B: 8x int4 = 128 B/thread

    float xv[2];
    int4 bv[8];
#define K1_PRELOAD(jb)                                                         \
    {                                                                          \
        _Pragma("unroll") for (int q = 0; q < 2; ++q)                          \
            xv[q] = HT[(size_t)((jb) + xf0 + q * 4) * 32768 + r0 + xrow];      \
        const int4* bgp = reinterpret_cast<const int4*>(                       \
            &Bp[(size_t)bn * 4096 + (jb) * 16 + bk0]);                         \
        _Pragma("unroll") for (int q = 0; q < 8; ++q) bv[q] = bgp[q];          \
    }

    f32x4 acc[2][4];
#pragma unroll
    for (int mt = 0; mt < 2; ++mt)
#pragma unroll
        for (int nt = 0; nt < 4; ++nt) acc[mt][nt] = (f32x4){0.f, 0.f, 0.f, 0.f};

    K1_PRELOAD(0);
    for (int jb = 0; jb < 256; jb += 8) {
        __syncthreads();   // prev MFMA done; LDS free
        // expand phi (silu + 8 bases + 7 pad = 16 bf16 per feature)
#pragma unroll
        for (int q = 0; q < 2; ++q) {
            const int f = xf0 + q * 4;
            const float x = xv[q];
            float bs[8];
            bspline8(x, bs);
            const uint32_t w0 = pack2(silu_f(x), bs[0]);
            const uint32_t w1 = pack2(bs[1], bs[2]);
            const uint32_t w2 = pack2(bs[3], bs[4]);
            const uint32_t w3 = pack2(bs[5], bs[6]);
            const uint32_t w4 = pack2(bs[7], 0.f);
            const uint32_t swz = (uint32_t)(xrow & 15) << 4;
            const uint32_t base = (uint32_t)xrow * 256u + (uint32_t)f * 32u;
            *reinterpret_cast<int4*>(smP + (base ^ swz)) =
                make_int4((int)w0, (int)w1, (int)w2, (int)w3);
            *reinterpret_cast<int4*>(smP + ((base + 16u) ^ swz)) =
                make_int4((int)w4, 0, 0, 0);
        }
        // write B tile
#pragma unroll
        for (int q = 0; q < 8; ++q) {
            uint32_t off = ((uint32_t)bn * 256u + (uint32_t)(bk0 + q * 8) * 2u) ^
                           ((uint32_t)(bn & 15) << 4);
            *reinterpret_cast<int4*>(smB + off) = bv[q];
        }
        __syncthreads();
        if (jb + 8 < 256) K1_PRELOAD(jb + 8);   // prefetch (flies under MFMA)
#pragma unroll
        for (int ks = 0; ks < 4; ++ks) {
            const int kb = ks * 32 + fkb;
            bf16x8 a[2], b[4];
#pragma unroll
            for (int mt = 0; mt < 2; ++mt) {
                uint32_t row = (uint32_t)(wr * 32 + mt * 16 + fr);
                uint32_t off = (row * 256u + (uint32_t)kb * 2u) ^ ((row & 15u) << 4);
                a[mt] = *reinterpret_cast<const bf16x8*>(smP + off);
            }
#pragma unroll
            for (int nt = 0; nt < 4; ++nt) {
                uint32_t n = (uint32_t)(wc * 64 + nt * 16 + fr);
                uint32_t off = (n * 256u + (uint32_t)kb * 2u) ^ ((n & 15u) << 4);
                b[nt] = *reinterpret_cast<const bf16x8*>(smB + off);
            }
#pragma unroll
            for (int mt = 0; mt < 2; ++mt)
#pragma unroll
                for (int nt = 0; nt < 4; ++nt)
                    acc[mt][nt] = __builtin_amdgcn_mfma_f32_16x16x32_bf16(
                        a[mt], b[nt], acc[mt][nt], 0, 0, 0);
        }
    }
    __syncthreads();
    // stash H2 tile (fp32) into LDS [64][132]
#pragma unroll
    for (int mt = 0; mt < 2; ++mt)
#pragma unroll
        for (int nt = 0; nt < 4; ++nt) {
            const int col = wc * 64 + nt * 16 + fr;
#pragma unroll
            for (int j = 0; j < 4; ++j) {
                const int row = wr * 32 + mt * 16 + h * 4 + j;
                smH[row * 132 + col] = acc[mt][nt][j];
            }
        }
    __syncthreads();
    // fused KAN2: 4 threads per row, 32 cols each, shfl reduce, sigmoid
    const int row = t >> 2, qd = t & 3;
    float sum = 0.f;
#pragma unroll 4
    for (int i = 0; i < 32; ++i) {
        const int j = qd * 32 + ((i + qd * 8) & 31);   // stagger to avoid bank conflict
        const float x = smH[row * 132 + j];
        float bs[8];
        bspline8(x, bs);
        const float4 s0 = *reinterpret_cast<const float4*>(&w2s[j * 8]);
        const float4 s1 = *reinterpret_cast<const float4*>(&w2s[j * 8 + 4]);
        float s = silu_f(x) * w2b[j];
        s += bs[0] * s0.x + bs[1] * s0.y + bs[2] * s0.z + bs[3] * s0.w;
        s += bs[4] * s1.x + bs[5] * s1.y + bs[6] * s1.z + bs[7] * s1.w;
        sum += s;
    }
    sum += __shfl_xor(sum, 1, 64);
    sum += __shfl_xor(sum, 2, 64);
    if (qd == 0) out[r0 + row] = 1.0f / (1.0f + __expf(-sum));
}

// ---------------------------------------------------------------------------
extern "C" void kernel_launch(void* const* d_in, const int* in_sizes, int n_in,
                              void* d_out, int out_size, void* d_ws, size_t ws_size,
                              hipStream_t stream) {
    const float* stm  = (const float*)d_in[0];
    const float* nstm = (const float*)d_in[1];
    const float* ft_w = (const float*)d_in[2];
    const float* ft_b = (const float*)d_in[3];
    const float* k1bw = (const float*)d_in[4];
    const float* k1sw = (const float*)d_in[5];
    const float* k2bw = (const float*)d_in[6];
    const float* k2sw = (const float*)d_in[7];
    float* out = (float*)d_out;

    char* ws = (char*)d_ws;
    float* HT = (float*)ws;                                           // 33,554,432 B
    unsigned short* Wb = (unsigned short*)(ws + 33554432);            //    196,608 B
    unsigned short* Bp = (unsigned short*)(ws + 33554432 + 196608);   //  1,048,576 B

    prep_ftw<<<384, 256, 0, stream>>>(ft_w, Wb);
    prep_bp<<<2048, 256, 0, stream>>>(k1bw, k1sw, Bp);
    ft_mfma<<<dim3(512, 2), 256, 0, stream>>>(stm, nstm, Wb, ft_b, HT);
    kan1_fused<<<512, 256, 0, stream>>>(HT, Bp, k2bw, k2sw, out);
}

// Round 4
// 145.444 us; speedup vs baseline: 2.1182x; 2.1182x over previous
//
#include <hip/hip_runtime.h>
#include <math.h>
#include <stdint.h>

typedef __attribute__((ext_vector_type(8))) short bf16x8;
typedef __attribute__((ext_vector_type(4))) float f32x4;

__device__ __forceinline__ unsigned short f2bf(float f) {
    union { float f; uint32_t u; } c; c.f = f;
    uint32_t u = c.u;
    u += 0x7FFFu + ((u >> 16) & 1u);
    return (unsigned short)(u >> 16);
}
__device__ __forceinline__ uint32_t pack2(float a, float b) {
    return (uint32_t)f2bf(a) | ((uint32_t)f2bf(b) << 16);
}
__device__ __forceinline__ float bf2f(unsigned short h) {
    union { uint32_t u; float f; } c; c.u = ((uint32_t)h) << 16;
    return c.f;
}
__device__ __forceinline__ float silu_f(float x) {
    return x / (1.0f + __expf(-x));
}

// Uniform cardinal cubic B-spline bases on grid g_i = -2.2 + 0.4*i.
// Identical to the reference Cox-de-Boor recursion on this uniform grid.
__device__ __forceinline__ void bspline8(float x, float* __restrict__ b) {
    const float tt = (x + 2.2f) * 2.5f;
#pragma unroll
    for (int v = 0; v < 8; ++v) {
        float y = fabsf(tt - (float)(v + 2));
        float p = fmaxf(2.0f - y, 0.0f);
        float q = fmaxf(1.0f - y, 0.0f);
        b[v] = (p * p * p - 4.0f * q * q * q) * (1.0f / 6.0f);
    }
}

// ---------------------------------------------------------------------------
// prep kernels
// ---------------------------------------------------------------------------
__global__ __launch_bounds__(256) void prep_ftw(const float* __restrict__ ftw,
                                                unsigned short* __restrict__ Wb) {
    const int idx = blockIdx.x * 256 + threadIdx.x;   // 98304 = 128*768
    Wb[idx] = f2bf(ftw[idx]);
}

__global__ __launch_bounds__(256) void prep_bp(const float* __restrict__ bw,
                                               const float* __restrict__ sw,
                                               unsigned short* __restrict__ Bp) {
    const int idx = blockIdx.x * 256 + threadIdx.x;   // 524288 = 128*4096
    const int n = idx >> 12;
    const int k = idx & 4095;
    const int f = k >> 4;
    const int v = k & 15;
    float val = 0.f;
    if (v == 0) val = bw[n * 256 + f];
    else if (v <= 8) val = sw[(size_t)(n * 256 + f) * 8 + (v - 1)];
    Bp[idx] = f2bf(val);
}

// ---------------------------------------------------------------------------
// FT GEMM (bf16 MFMA), BM=128, BK=64, block 512 (8 waves as 2x4; wave 64x32).
// Direct global->LDS staging (no held prefetch regs).  Output transposed:
// HT[c][r], c = side*128 + o.  grid (256, 2).
// ---------------------------------------------------------------------------
__global__ __launch_bounds__(512) void ft_mfma(
        const float* __restrict__ stm, const float* __restrict__ nstm,
        const unsigned short* __restrict__ Wb, const float* __restrict__ bias,
        float* __restrict__ HT) {
    __shared__ char lds[32768];          // smA 16 KB | smB 16 KB
    char* smA = lds;
    char* smB = lds + 16384;
    const int side = blockIdx.y;
    const float* __restrict__ A = side ? nstm : stm;
    const int r0 = blockIdx.x * 128;
    const int t = threadIdx.x;
    const int lane = t & 63, wid = t >> 6;
    const int wr = wid >> 2, wc = wid & 3;     // 2 x 4 waves
    const int fr = lane & 15;
    const int h = lane >> 4;                   // 0..3
    const int fkb = h * 8;

    const int arow = t >> 2, ako = (t & 3) * 16;   // A: 16 floats (64 B contiguous)
    const int bcol = t >> 2, bko = (t & 3) * 16;   // B: 16 bf16 (32 B contiguous)

    f32x4 acc[4][2];
#pragma unroll
    for (int mt = 0; mt < 4; ++mt)
#pragma unroll
        for (int nt = 0; nt < 2; ++nt) acc[mt][nt] = (f32x4){0.f, 0.f, 0.f, 0.f};

    for (int k0 = 0; k0 < 768; k0 += 64) {
        // stage A (fp32 -> bf16), 2x int4 LDS writes
        {
            const float4* ap = reinterpret_cast<const float4*>(
                &A[(size_t)(r0 + arow) * 768 + k0 + ako]);
#pragma unroll
            for (int q = 0; q < 2; ++q) {
                float4 u = ap[2 * q], v = ap[2 * q + 1];
                int4 w;
                w.x = (int)pack2(u.x, u.y); w.y = (int)pack2(u.z, u.w);
                w.z = (int)pack2(v.x, v.y); w.w = (int)pack2(v.z, v.w);
                uint32_t off = ((uint32_t)arow * 128u +
                                (uint32_t)(ako + q * 8) * 2u) ^
                               ((uint32_t)(arow & 7) << 4);
                *reinterpret_cast<int4*>(smA + off) = w;
            }
        }
        // stage B (already bf16), 2x int4
        {
            const int4* bp = reinterpret_cast<const int4*>(
                &Wb[(size_t)bcol * 768 + k0 + bko]);
#pragma unroll
            for (int q = 0; q < 2; ++q) {
                int4 w = bp[q];
                uint32_t off = ((uint32_t)bcol * 128u +
                                (uint32_t)(bko + q * 8) * 2u) ^
                               ((uint32_t)(bcol & 7) << 4);
                *reinterpret_cast<int4*>(smB + off) = w;
            }
        }
        __syncthreads();
#pragma unroll
        for (int ks = 0; ks < 2; ++ks) {
            const int kb = ks * 32 + fkb;
            bf16x8 a[4], b[2];
#pragma unroll
            for (int mt = 0; mt < 4; ++mt) {
                uint32_t row = (uint32_t)(wr * 64 + mt * 16 + fr);
                uint32_t off = (row * 128u + (uint32_t)kb * 2u) ^ ((row & 7u) << 4);
                a[mt] = *reinterpret_cast<const bf16x8*>(smA + off);
            }
#pragma unroll
            for (int nt = 0; nt < 2; ++nt) {
                uint32_t col = (uint32_t)(wc * 32 + nt * 16 + fr);
                uint32_t off = (col * 128u + (uint32_t)kb * 2u) ^ ((col & 7u) << 4);
                b[nt] = *reinterpret_cast<const bf16x8*>(smB + off);
            }
#pragma unroll
            for (int mt = 0; mt < 4; ++mt)
#pragma unroll
                for (int nt = 0; nt < 2; ++nt)
                    acc[mt][nt] = __builtin_amdgcn_mfma_f32_16x16x32_bf16(
                        a[mt], b[nt], acc[mt][nt], 0, 0, 0);
        }
        __syncthreads();
    }
    // epilogue: HT[c][r], float4 over 4 consecutive rows
#pragma unroll
    for (int nt = 0; nt < 2; ++nt) {
        const int colL = wc * 32 + nt * 16 + fr;
        const float bv = bias[colL];
        const size_t cg = (size_t)(side * 128 + colL) * 32768;
#pragma unroll
        for (int mt = 0; mt < 4; ++mt) {
            const int row = r0 + wr * 64 + mt * 16 + h * 4;
            float4 o;
            o.x = acc[mt][nt][0] + bv; o.y = acc[mt][nt][1] + bv;
            o.z = acc[mt][nt][2] + bv; o.w = acc[mt][nt][3] + bv;
            *reinterpret_cast<float4*>(&HT[cg + row]) = o;
        }
    }
}

// ---------------------------------------------------------------------------
// KAN1 (bf16 MFMA, expanded A, K=256*16) + fused KAN2 + sigmoid.
// BM=128, K-step=128 (8 features), block 512 (8 waves as 2x4), grid 256.
// Direct global->LDS staging (round-2 structure; no held prefetch regs).
// ---------------------------------------------------------------------------
__global__ __launch_bounds__(512) void kan1_fused(
        const float* __restrict__ HT,           // 256 x 32768 f32 (transposed)
        const unsigned short* __restrict__ Bp,  // 128 x 4096 bf16 (padded)
        const float* __restrict__ w2b,          // 128
        const float* __restrict__ w2s,          // 128 x 8
        float* __restrict__ out) {              // 32768
    __shared__ char lds[65536];   // smP 32 KB | smB 32 KB ; epilogue: smH bf16 128x136
    char* smP = lds;
    char* smB = lds + 32768;
    unsigned short* smH = (unsigned short*)lds;
    const int r0 = blockIdx.x * 128;
    const int t = threadIdx.x;
    const int lane = t & 63, wid = t >> 6;
    const int wr = wid >> 2, wc = wid & 3;     // 2 x 4 waves
    const int fr = lane & 15;
    const int h = lane >> 4;
    const int fkb = h * 8;

    const int xrow = t & 127, xf0 = t >> 7;    // x: coalesced over rows
    const int bn = t >> 2, bk0 = (t & 3) * 32; // B: 64 B contiguous per thread

    f32x4 acc[4][2];
#pragma unroll
    for (int mt = 0; mt < 4; ++mt)
#pragma unroll
        for (int nt = 0; nt < 2; ++nt) acc[mt][nt] = (f32x4){0.f, 0.f, 0.f, 0.f};

    for (int jb = 0; jb < 256; jb += 8) {
        // expand phi: 2 (row, feature) pairs per thread, coalesced HT reads
#pragma unroll
        for (int q = 0; q < 2; ++q) {
            const int f = xf0 + q * 4;
            const float x = HT[(size_t)(jb + f) * 32768 + r0 + xrow];
            float bs[8];
            bspline8(x, bs);
            const uint32_t w0 = pack2(silu_f(x), bs[0]);
            const uint32_t w1 = pack2(bs[1], bs[2]);
            const uint32_t w2 = pack2(bs[3], bs[4]);
            const uint32_t w3 = pack2(bs[5], bs[6]);
            const uint32_t w4 = pack2(bs[7], 0.f);
            const uint32_t swz = (uint32_t)(xrow & 15) << 4;
            const uint32_t base = (uint32_t)xrow * 256u + (uint32_t)f * 32u;
            *reinterpret_cast<int4*>(smP + (base ^ swz)) =
                make_int4((int)w0, (int)w1, (int)w2, (int)w3);
            *reinterpret_cast<int4*>(smP + ((base + 16u) ^ swz)) =
                make_int4((int)w4, 0, 0, 0);
        }
        // stage B tile: 4x int4 per thread
        {
            const int4* bgp = reinterpret_cast<const int4*>(
                &Bp[(size_t)bn * 4096 + jb * 16 + bk0]);
#pragma unroll
            for (int q = 0; q < 4; ++q) {
                int4 w = bgp[q];
                uint32_t off = ((uint32_t)bn * 256u +
                                (uint32_t)(bk0 + q * 8) * 2u) ^
                               ((uint32_t)(bn & 15) << 4);
                *reinterpret_cast<int4*>(smB + off) = w;
            }
        }
        __syncthreads();
#pragma unroll
        for (int ks = 0; ks < 4; ++ks) {
            const int kb = ks * 32 + fkb;
            bf16x8 a[4], b[2];
#pragma unroll
            for (int mt = 0; mt < 4; ++mt) {
                uint32_t row = (uint32_t)(wr * 64 + mt * 16 + fr);
                uint32_t off = (row * 256u + (uint32_t)kb * 2u) ^ ((row & 15u) << 4);
                a[mt] = *reinterpret_cast<const bf16x8*>(smP + off);
            }
#pragma unroll
            for (int nt = 0; nt < 2; ++nt) {
                uint32_t n = (uint32_t)(wc * 32 + nt * 16 + fr);
                uint32_t off = (n * 256u + (uint32_t)kb * 2u) ^ ((n & 15u) << 4);
                b[nt] = *reinterpret_cast<const bf16x8*>(smB + off);
            }
#pragma unroll
            for (int mt = 0; mt < 4; ++mt)
#pragma unroll
                for (int nt = 0; nt < 2; ++nt)
                    acc[mt][nt] = __builtin_amdgcn_mfma_f32_16x16x32_bf16(
                        a[mt], b[nt], acc[mt][nt], 0, 0, 0);
        }
        __syncthreads();
    }
    // stash H2 tile (bf16) into LDS [128][136]
#pragma unroll
    for (int mt = 0; mt < 4; ++mt)
#pragma unroll
        for (int nt = 0; nt < 2; ++nt) {
            const int col = wc * 32 + nt * 16 + fr;
#pragma unroll
            for (int j = 0; j < 4; ++j) {
                const int row = wr * 64 + mt * 16 + h * 4 + j;
                smH[row * 136 + col] = f2bf(acc[mt][nt][j]);
            }
        }
    __syncthreads();
    // fused KAN2: 4 threads per row, 32 cols each, shfl reduce, sigmoid
    const int row = t >> 2, qd = t & 3;
    float sum = 0.f;
#pragma unroll 4
    for (int i = 0; i < 32; ++i) {
        const int j = qd * 32 + ((i + qd * 8) & 31);   // stagger banks
        const float x = bf2f(smH[row * 136 + j]);
        float bs[8];
        bspline8(x, bs);
        const float4 s0 = *reinterpret_cast<const float4*>(&w2s[j * 8]);
        const float4 s1 = *reinterpret_cast<const float4*>(&w2s[j * 8 + 4]);
        float s = silu_f(x) * w2b[j];
        s += bs[0] * s0.x + bs[1] * s0.y + bs[2] * s0.z + bs[3] * s0.w;
        s += bs[4] * s1.x + bs[5] * s1.y + bs[6] * s1.z + bs[7] * s1.w;
        sum += s;
    }
    sum += __shfl_xor(sum, 1, 64);
    sum += __shfl_xor(sum, 2, 64);
    if (qd == 0) out[r0 + row] = 1.0f / (1.0f + __expf(-sum));
}

// ---------------------------------------------------------------------------
extern "C" void kernel_launch(void* const* d_in, const int* in_sizes, int n_in,
                              void* d_out, int out_size, void* d_ws, size_t ws_size,
                              hipStream_t stream) {
    const float* stm  = (const float*)d_in[0];
    const float* nstm = (const float*)d_in[1];
    const float* ft_w = (const float*)d_in[2];
    const float* ft_b = (const float*)d_in[3];
    const float* k1bw = (const float*)d_in[4];
    const float* k1sw = (const float*)d_in[5];
    const float* k2bw = (const float*)d_in[6];
    const float* k2sw = (const float*)d_in[7];
    float* out = (float*)d_out;

    char* ws = (char*)d_ws;
    float* HT = (float*)ws;                                           // 33,554,432 B
    unsigned short* Wb = (unsigned short*)(ws + 33554432);            //    196,608 B
    unsigned short* Bp = (unsigned short*)(ws + 33554432 + 196608);   //  1,048,576 B

    prep_ftw<<<384, 256, 0, stream>>>(ft_w, Wb);
    prep_bp<<<2048, 256, 0, stream>>>(k1bw, k1sw, Bp);
    ft_mfma<<<dim3(256, 2), 512, 0, stream>>>(stm, nstm, Wb, ft_b, HT);
    kan1_fused<<<256, 512, 0, stream>>>(HT, Bp, k2bw, k2sw, out);
}

// Round 5
// 127.243 us; speedup vs baseline: 2.4212x; 1.1430x over previous
//
#include <hip/hip_runtime.h>
#include <hip/hip_bf16.h>
#include <math.h>
#include <stdint.h>

typedef __attribute__((ext_vector_type(8))) short bf16x8;
typedef __attribute__((ext_vector_type(4))) float f32x4;

__device__ __forceinline__ uint32_t pack2(float a, float b) {
    union { __hip_bfloat162 h2; uint32_t u; } c;
    c.h2 = __float22bfloat162_rn(make_float2(a, b));   // v_cvt_pk_bf16_f32
    return c.u;
}
__device__ __forceinline__ unsigned short f2bf(float f) {
    union { __hip_bfloat16 h; unsigned short u; } c;
    c.h = __float2bfloat16(f);
    return c.u;
}
__device__ __forceinline__ float bf2f(unsigned short h) {
    union { uint32_t u; float f; } c; c.u = ((uint32_t)h) << 16;
    return c.f;
}
__device__ __forceinline__ float silu_f(float x) {
    return x / (1.0f + __expf(-x));
}

// Uniform cardinal cubic B-spline bases on grid g_i = -2.2 + 0.4*i.
// Identical to the reference Cox-de-Boor recursion on this uniform grid.
__device__ __forceinline__ void bspline8(float x, float* __restrict__ b) {
    const float tt = (x + 2.2f) * 2.5f;
#pragma unroll
    for (int v = 0; v < 8; ++v) {
        float y = fabsf(tt - (float)(v + 2));
        float p = fmaxf(2.0f - y, 0.0f);
        float q = fmaxf(1.0f - y, 0.0f);
        b[v] = (p * p * p - 4.0f * q * q * q) * (1.0f / 6.0f);
    }
}

// ---------------------------------------------------------------------------
// prep kernels
// ---------------------------------------------------------------------------
__global__ __launch_bounds__(256) void prep_ftw(const float* __restrict__ ftw,
                                                unsigned short* __restrict__ Wb) {
    const int idx = blockIdx.x * 256 + threadIdx.x;   // 98304 = 128*768
    Wb[idx] = f2bf(ftw[idx]);
}

__global__ __launch_bounds__(256) void prep_bp(const float* __restrict__ bw,
                                               const float* __restrict__ sw,
                                               unsigned short* __restrict__ Bp) {
    const int idx = blockIdx.x * 256 + threadIdx.x;   // 524288 = 128*4096
    const int n = idx >> 12;
    const int k = idx & 4095;
    const int f = k >> 4;
    const int v = k & 15;
    float val = 0.f;
    if (v == 0) val = bw[n * 256 + f];
    else if (v <= 8) val = sw[(size_t)(n * 256 + f) * 8 + (v - 1)];
    Bp[idx] = f2bf(val);
}

// ---------------------------------------------------------------------------
// FT GEMM (bf16 MFMA), BM=128, BK=64, block 512 (8 waves as 2x4; wave 64x32).
// Output transposed: HT[c][r], c = side*128 + o.  grid (256, 2).
// ---------------------------------------------------------------------------
__global__ __launch_bounds__(512) void ft_mfma(
        const float* __restrict__ stm, const float* __restrict__ nstm,
        const unsigned short* __restrict__ Wb, const float* __restrict__ bias,
        float* __restrict__ HT) {
    __shared__ char lds[32768];          // smA 16 KB | smB 16 KB
    char* smA = lds;
    char* smB = lds + 16384;
    const int side = blockIdx.y;
    const float* __restrict__ A = side ? nstm : stm;
    const int r0 = blockIdx.x * 128;
    const int t = threadIdx.x;
    const int lane = t & 63, wid = t >> 6;
    const int wr = wid >> 2, wc = wid & 3;     // 2 x 4 waves
    const int fr = lane & 15;
    const int h = lane >> 4;                   // 0..3
    const int fkb = h * 8;

    const int arow = t >> 2, ako = (t & 3) * 16;   // A: 16 floats (64 B contiguous)
    const int bcol = t >> 2, bko = (t & 3) * 16;   // B: 16 bf16 (32 B contiguous)

    f32x4 acc[4][2];
#pragma unroll
    for (int mt = 0; mt < 4; ++mt)
#pragma unroll
        for (int nt = 0; nt < 2; ++nt) acc[mt][nt] = (f32x4){0.f, 0.f, 0.f, 0.f};

    for (int k0 = 0; k0 < 768; k0 += 64) {
        // stage A (fp32 -> bf16 via cvt_pk), 2x int4 LDS writes
        {
            const float4* ap = reinterpret_cast<const float4*>(
                &A[(size_t)(r0 + arow) * 768 + k0 + ako]);
#pragma unroll
            for (int q = 0; q < 2; ++q) {
                float4 u = ap[2 * q], v = ap[2 * q + 1];
                int4 w;
                w.x = (int)pack2(u.x, u.y); w.y = (int)pack2(u.z, u.w);
                w.z = (int)pack2(v.x, v.y); w.w = (int)pack2(v.z, v.w);
                uint32_t off = ((uint32_t)arow * 128u +
                                (uint32_t)(ako + q * 8) * 2u) ^
                               ((uint32_t)(arow & 7) << 4);
                *reinterpret_cast<int4*>(smA + off) = w;
            }
        }
        // stage B (already bf16), 2x int4
        {
            const int4* bp = reinterpret_cast<const int4*>(
                &Wb[(size_t)bcol * 768 + k0 + bko]);
#pragma unroll
            for (int q = 0; q < 2; ++q) {
                int4 w = bp[q];
                uint32_t off = ((uint32_t)bcol * 128u +
                                (uint32_t)(bko + q * 8) * 2u) ^
                               ((uint32_t)(bcol & 7) << 4);
                *reinterpret_cast<int4*>(smB + off) = w;
            }
        }
        __syncthreads();
#pragma unroll
        for (int ks = 0; ks < 2; ++ks) {
            const int kb = ks * 32 + fkb;
            bf16x8 a[4], b[2];
#pragma unroll
            for (int mt = 0; mt < 4; ++mt) {
                uint32_t row = (uint32_t)(wr * 64 + mt * 16 + fr);
                uint32_t off = (row * 128u + (uint32_t)kb * 2u) ^ ((row & 7u) << 4);
                a[mt] = *reinterpret_cast<const bf16x8*>(smA + off);
            }
#pragma unroll
            for (int nt = 0; nt < 2; ++nt) {
                uint32_t col = (uint32_t)(wc * 32 + nt * 16 + fr);
                uint32_t off = (col * 128u + (uint32_t)kb * 2u) ^ ((col & 7u) << 4);
                b[nt] = *reinterpret_cast<const bf16x8*>(smB + off);
            }
#pragma unroll
            for (int mt = 0; mt < 4; ++mt)
#pragma unroll
                for (int nt = 0; nt < 2; ++nt)
                    acc[mt][nt] = __builtin_amdgcn_mfma_f32_16x16x32_bf16(
                        a[mt], b[nt], acc[mt][nt], 0, 0, 0);
        }
        __syncthreads();
    }
    // epilogue: HT[c][r], float4 over 4 consecutive rows
#pragma unroll
    for (int nt = 0; nt < 2; ++nt) {
        const int colL = wc * 32 + nt * 16 + fr;
        const float bv = bias[colL];
        const size_t cg = (size_t)(side * 128 + colL) * 32768;
#pragma unroll
        for (int mt = 0; mt < 4; ++mt) {
            const int row = r0 + wr * 64 + mt * 16 + h * 4;
            float4 o;
            o.x = acc[mt][nt][0] + bv; o.y = acc[mt][nt][1] + bv;
            o.z = acc[mt][nt][2] + bv; o.w = acc[mt][nt][3] + bv;
            *reinterpret_cast<float4*>(&HT[cg + row]) = o;
        }
    }
}

// ---------------------------------------------------------------------------
// KAN1 (bf16 MFMA, expanded A, K=256*16) + fused KAN2 + sigmoid.
// BM=64, K-step=128 (8 features), block 512 (8 waves as 2x4; wave 32x32).
// grid 512 -> 2 blocks/CU, 16 waves/CU.
// ---------------------------------------------------------------------------
__global__ __launch_bounds__(512) void kan1_fused(
        const float* __restrict__ HT,           // 256 x 32768 f32 (transposed)
        const unsigned short* __restrict__ Bp,  // 128 x 4096 bf16 (padded)
        const float* __restrict__ w2b,          // 128
        const float* __restrict__ w2s,          // 128 x 8
        float* __restrict__ out) {              // 32768
    __shared__ char lds[49152];   // smP 16 KB | smB 32 KB ; epilogue: smH bf16 64x136
    char* smP = lds;
    char* smB = lds + 16384;
    unsigned short* smH = (unsigned short*)lds;
    const int r0 = blockIdx.x * 64;
    const int t = threadIdx.x;
    const int lane = t & 63, wid = t >> 6;
    const int wr = wid >> 2, wc = wid & 3;     // 2 x 4 waves; wave tile 32x32
    const int fr = lane & 15;
    const int h = lane >> 4;
    const int fkb = h * 8;

    const int xrow = t & 63, xf = t >> 6;      // 1 expansion per thread
    const int bn = t >> 2, bk0 = (t & 3) * 32; // B: 64 B contiguous per thread

    f32x4 acc[2][2];
#pragma unroll
    for (int mt = 0; mt < 2; ++mt)
#pragma unroll
        for (int nt = 0; nt < 2; ++nt) acc[mt][nt] = (f32x4){0.f, 0.f, 0.f, 0.f};

    for (int jb = 0; jb < 256; jb += 8) {
        // expand phi: one (row, feature) pair per thread, coalesced HT read
        {
            const float x = HT[(size_t)(jb + xf) * 32768 + r0 + xrow];
            float bs[8];
            bspline8(x, bs);
            const uint32_t w0 = pack2(silu_f(x), bs[0]);
            const uint32_t w1 = pack2(bs[1], bs[2]);
            const uint32_t w2 = pack2(bs[3], bs[4]);
            const uint32_t w3 = pack2(bs[5], bs[6]);
            const uint32_t w4 = pack2(bs[7], 0.f);
            const uint32_t swz = (uint32_t)(xrow & 15) << 4;
            const uint32_t base = (uint32_t)xrow * 256u + (uint32_t)xf * 32u;
            *reinterpret_cast<int4*>(smP + (base ^ swz)) =
                make_int4((int)w0, (int)w1, (int)w2, (int)w3);
            *reinterpret_cast<int4*>(smP + ((base + 16u) ^ swz)) =
                make_int4((int)w4, 0, 0, 0);
        }
        // stage B tile: 4x int4 per thread
        {
            const int4* bgp = reinterpret_cast<const int4*>(
                &Bp[(size_t)bn * 4096 + jb * 16 + bk0]);
#pragma unroll
            for (int q = 0; q < 4; ++q) {
                int4 w = bgp[q];
                uint32_t off = ((uint32_t)bn * 256u +
                                (uint32_t)(bk0 + q * 8) * 2u) ^
                               ((uint32_t)(bn & 15) << 4);
                *reinterpret_cast<int4*>(smB + off) = w;
            }
        }
        __syncthreads();
        __builtin_amdgcn_s_setprio(1);
#pragma unroll
        for (int ks = 0; ks < 4; ++ks) {
            const int kb = ks * 32 + fkb;
            bf16x8 a[2], b[2];
#pragma unroll
            for (int mt = 0; mt < 2; ++mt) {
                uint32_t row = (uint32_t)(wr * 32 + mt * 16 + fr);
                uint32_t off = (row * 256u + (uint32_t)kb * 2u) ^ ((row & 15u) << 4);
                a[mt] = *reinterpret_cast<const bf16x8*>(smP + off);
            }
#pragma unroll
            for (int nt = 0; nt < 2; ++nt) {
                uint32_t n = (uint32_t)(wc * 32 + nt * 16 + fr);
                uint32_t off = (n * 256u + (uint32_t)kb * 2u) ^ ((n & 15u) << 4);
                b[nt] = *reinterpret_cast<const bf16x8*>(smB + off);
            }
#pragma unroll
            for (int mt = 0; mt < 2; ++mt)
#pragma unroll
                for (int nt = 0; nt < 2; ++nt)
                    acc[mt][nt] = __builtin_amdgcn_mfma_f32_16x16x32_bf16(
                        a[mt], b[nt], acc[mt][nt], 0, 0, 0);
        }
        __builtin_amdgcn_s_setprio(0);
        __syncthreads();
    }
    // stash H2 tile (bf16) into LDS [64][136]
#pragma unroll
    for (int mt = 0; mt < 2; ++mt)
#pragma unroll
        for (int nt = 0; nt < 2; ++nt) {
            const int col = wc * 32 + nt * 16 + fr;
#pragma unroll
            for (int j = 0; j < 4; ++j) {
                const int row = wr * 32 + mt * 16 + h * 4 + j;
                smH[row * 136 + col] = f2bf(acc[mt][nt][j]);
            }
        }
    __syncthreads();
    // fused KAN2: 8 threads per row, 16 cols each, shfl reduce, sigmoid
    const int row = t >> 3, qd = t & 7;
    float sum = 0.f;
#pragma unroll 4
    for (int i = 0; i < 16; ++i) {
        const int j = qd * 16 + ((i + qd * 2) & 15);   // stagger banks
        const float x = bf2f(smH[row * 136 + j]);
        float bs[8];
        bspline8(x, bs);
        const float4 s0 = *reinterpret_cast<const float4*>(&w2s[j * 8]);
        const float4 s1 = *reinterpret_cast<const float4*>(&w2s[j * 8 + 4]);
        float s = silu_f(x) * w2b[j];
        s += bs[0] * s0.x + bs[1] * s0.y + bs[2] * s0.z + bs[3] * s0.w;
        s += bs[4] * s1.x + bs[5] * s1.y + bs[6] * s1.z + bs[7] * s1.w;
        sum += s;
    }
    sum += __shfl_xor(sum, 1, 64);
    sum += __shfl_xor(sum, 2, 64);
    sum += __shfl_xor(sum, 4, 64);
    if (qd == 0) out[r0 + row] = 1.0f / (1.0f + __expf(-sum));
}

// ---------------------------------------------------------------------------
extern "C" void kernel_launch(void* const* d_in, const int* in_sizes, int n_in,
                              void* d_out, int out_size, void* d_ws, size_t ws_size,
                              hipStream_t stream) {
    const float* stm  = (const float*)d_in[0];
    const float* nstm = (const float*)d_in[1];
    const float* ft_w = (const float*)d_in[2];
    const float* ft_b = (const float*)d_in[3];
    const float* k1bw = (const float*)d_in[4];
    const float* k1sw = (const float*)d_in[5];
    const float* k2bw = (const float*)d_in[6];
    const float* k2sw = (const float*)d_in[7];
    float* out = (float*)d_out;

    char* ws = (char*)d_ws;
    float* HT = (float*)ws;                                           // 33,554,432 B
    unsigned short* Wb = (unsigned short*)(ws + 33554432);            //    196,608 B
    unsigned short* Bp = (unsigned short*)(ws + 33554432 + 196608);   //  1,048,576 B

    prep_ftw<<<384, 256, 0, stream>>>(ft_w, Wb);
    prep_bp<<<2048, 256, 0, stream>>>(k1bw, k1sw, Bp);
    ft_mfma<<<dim3(256, 2), 512, 0, stream>>>(stm, nstm, Wb, ft_b, HT);
    kan1_fused<<<512, 512, 0, stream>>>(HT, Bp, k2bw, k2sw, out);
}